// Round 13
// baseline (2706.583 us; speedup 1.0000x reference)
//
#include <hip/hip_runtime.h>
#include <hip/hip_bf16.h>

typedef __attribute__((ext_vector_type(8))) short short8;
typedef __attribute__((ext_vector_type(4))) float f32x4;
typedef unsigned long long u64;

#define V_N 10000
#define D_E 128
#define H_N 512
#define B_N 32
#define S_N 512

#define SENT64 0xFFFFFFFFFFFFFFFFull   // 4x bf16 NaN: unreachable for finite h

// ---- workspace layout (bytes) ----
#define OFF_RP    0                        // rowpart: 16384 rows x 80 slots f32 = 5,242,880
#define OFF_EMB   5242880                  // S*B*D bf16 = 4,194,304
#define OFF_HS    (OFF_EMB + 4194304)      // S*B*H bf16 = 16,777,216
#define OFF_WOUT  (OFF_HS + 16777216)      // V*H bf16 = 10,240,000

// ------------------------------------------------------------------
__device__ __forceinline__ float ftanh(float x) {
  float e = __expf(-2.f * fabsf(x));          // in (0,1], overflow-safe
  float r = (1.f - e) / (1.f + e);
  return __builtin_copysignf(r, x);
}

union U128 { f32x4 f; u64 q[2]; };

// ------------------------------------------------------------------
// prep: embedding gather -> bf16 [s][b][d]
__global__ void k_prep_emb(const int* __restrict__ x, const float* __restrict__ tab,
                           __hip_bfloat16* __restrict__ emb) {
  int i = blockIdx.x * 256 + threadIdx.x;         // over S*B*D = 2,097,152
  if (i >= S_N * B_N * D_E) return;
  int d  = i & (D_E - 1);
  int sb = i >> 7;
  int b  = sb & (B_N - 1);
  int s  = sb >> 5;
  int tok = x[b * S_N + s];
  emb[i] = __float2bfloat16(tab[tok * D_E + d]);
}

// prep: W_out -> bf16
__global__ void k_prep_wout(const float* __restrict__ w, __hip_bfloat16* __restrict__ o) {
  int i = blockIdx.x * 256 + threadIdx.x;
  if (i < V_N * H_N) o[i] = __float2bfloat16(w[i]);
}

// ------------------------------------------------------------------
// persistent recurrence: 32 WGs x 512 threads (r12 structure).
// Poll upgraded: two pipelined chunk groups A={0,1} B={2,3} with counted
// vmcnt waits -- A's check overlaps B's flight, halving detection
// quantization vs full-drain sweeps. FIFO vmcnt semantics guarantee
// "wait vmcnt(nOther)" = oldest group returned.
__launch_bounds__(512, 1)
__global__ void k_recurrence(const int* __restrict__ x,
                             const float* __restrict__ W_ih, const float* __restrict__ W_hh,
                             const float* __restrict__ b_ih, const float* __restrict__ b_hh,
                             const __hip_bfloat16* __restrict__ emb,
                             __hip_bfloat16* __restrict__ hs)     // [512][32][512]
{
  __shared__ __align__(16) __hip_bfloat16 Bl[32][648];  // [example][emb128 ; h512]
  __shared__ float gl[128][34];            // [gate row][example] full-K gates
  __shared__ float bias[128];
  __shared__ unsigned short hloc[16][32];  // [jj][ex] bf16 bits of new h

  const int tid = threadIdx.x;
  const int wg  = blockIdx.x;              // 0..31
  const int lane = tid & 63, wv = tid >> 6;       // wv = wave 0..7 = row-group
  const int lrow = lane & 15, lk = (lane >> 4) * 8;
  const int b_ep = tid & 31, jj_ep = tid >> 5;    // epilogue map: 32 ex x 16 dims

  // ---- one-time: A-fragments (16 rows x full K 640) into registers ----
  short8 Afrag[20];                        // 80 VGPRs
  #pragma unroll
  for (int ks = 0; ks < 20; ++ks) {
    int lr = wv * 16 + lrow;               // local gate row 0..127
    int q = lr >> 5, kc = (lr >> 4) & 1, jj = lr & 15;
    int grow = kc * 2048 + q * 512 + wg * 16 + jj;
    int c0 = ks * 32 + lk;
    short8 a;
    #pragma unroll
    for (int e = 0; e < 8; ++e) {
      int c = c0 + e;
      float v = (c < 128) ? W_ih[(size_t)grow * 128 + c]
                          : W_hh[(size_t)grow * 512 + (c - 128)];
      __hip_bfloat16 hb = __float2bfloat16(v);
      a[e] = *(const short*)&hb;
    }
    Afrag[ks] = a;
  }
  if (tid < 128) {
    int lr = tid;
    int q = lr >> 5, kc = (lr >> 4) & 1, jj = lr & 15;
    int grow = kc * 2048 + q * 512 + wg * 16 + jj;
    bias[lr] = b_ih[grow] + b_hh[grow];
  }

  // ---- preload token parity bits (b_ep's row of x) ----
  unsigned par[16];
  #pragma unroll
  for (int w = 0; w < 16; ++w) {
    unsigned p = 0;
    for (int bb = 0; bb < 32; ++bb)
      p |= (unsigned)(x[b_ep * S_N + w * 32 + bb] & 1) << bb;
    par[w] = p;
  }

  float c_state = 0.f;                         // carry for (b_ep, jj_ep)

  for (int t = 0; t < S_N; ++t) {
    // ---- stage emb_t: 1 x 16B cached load/thread (512 chunks) ----
    {
      const f32x4* e16 = (const f32x4*)(emb + (size_t)t * B_N * D_E);
      int ex = tid >> 4, col = tid & 15;
      *(f32x4*)((char*)&Bl[0][0] + ex * 1296 + col * 16) = e16[tid];
    }
    // ---- stage h_prev: pipelined 2-group sentinel poll ----
    if (t == 0) {
      for (int i = tid; i < 4096; i += 512) {
        int b = i >> 7, hh = i & 127;
        *(u64*)&Bl[b][128 + hh * 4] = 0ull;
      }
    } else {
      const char* srcb = (const char*)hs + (size_t)(t - 1) * 32768;
      U128 buf[4];
#define ISSUE(c) asm volatile("global_load_dwordx4 %0, %1, off sc0 sc1" \
        : "=v"(buf[c].f) : "v"(srcb + ((c) * 8192 + tid * 16)) : "memory")
#define WAITN(n) do { int _n = (n); \
        if (_n == 0)      asm volatile("s_waitcnt vmcnt(0)" ::: "memory"); \
        else if (_n == 1) asm volatile("s_waitcnt vmcnt(1)" ::: "memory"); \
        else              asm volatile("s_waitcnt vmcnt(2)" ::: "memory"); \
        __builtin_amdgcn_sched_barrier(0); } while (0)
#define CHK(c, bit) if ((pend & (bit)) && buf[c].q[0] != SENT64 && buf[c].q[1] != SENT64) { \
        int ci = (c) * 512 + tid; \
        *(f32x4*)((char*)&Bl[0][0] + (ci >> 6) * 1296 + 256 + (ci & 63) * 16) = buf[c].f; \
        pend &= ~(unsigned)(bit); }
      unsigned pend = 0xFu;
      int nA = 2, nB = 2;
      ISSUE(0); ISSUE(1); ISSUE(2); ISSUE(3);
      while (pend) {
        WAITN(nB);                         // group A returned (B still flying)
        CHK(0, 1u) CHK(1, 2u)
        nA = 0;
        if (pend & 1u) { ISSUE(0); ++nA; }
        if (pend & 2u) { ISSUE(1); ++nA; }
        WAITN(nA);                         // group B returned (A reissues flying)
        CHK(2, 4u) CHK(3, 8u)
        nB = 0;
        if (pend & 4u) { ISSUE(2); ++nB; }
        if (pend & 8u) { ISSUE(3); ++nB; }
      }
#undef ISSUE
#undef WAITN
#undef CHK
    }
    __syncthreads();                 // A: B ready

    // ---- MFMA: wave wv: rows [wv*16,+16) x 32 ex over full K=640 ----
    {
      f32x4 acc0 = {0.f,0.f,0.f,0.f}, acc1 = {0.f,0.f,0.f,0.f};
      #pragma unroll
      for (int ks = 0; ks < 20; ++ks) {
        int cb = (ks * 32 + lk) * 2;       // byte offset in a row
        short8 b0 = *(const short8*)((const char*)&Bl[0][0] + lrow * 1296 + cb);
        short8 b1 = *(const short8*)((const char*)&Bl[0][0] + (16 + lrow) * 1296 + cb);
        acc0 = __builtin_amdgcn_mfma_f32_16x16x32_bf16(Afrag[ks], b0, acc0, 0, 0, 0);
        acc1 = __builtin_amdgcn_mfma_f32_16x16x32_bf16(Afrag[ks], b1, acc1, 0, 0, 0);
      }
      int r0 = wv * 16 + (lane >> 4) * 4;
      int cb0 = lane & 15;
      #pragma unroll
      for (int r = 0; r < 4; ++r) {
        gl[r0 + r][cb0]      = acc0[r];
        gl[r0 + r][16 + cb0] = acc1[r];
      }
    }
    __syncthreads();                 // B: all gates ready (full K, no partials)

    // ---- epilogue: thread <-> (b_ep, jj_ep in 0..15) ----
    {
      float cand_c[2], cand_h[2];
      #pragma unroll
      for (int kc = 0; kc < 2; ++kc) {
        int base = kc * 16 + jj_ep;
        float ig = gl[base][b_ep]      + bias[base];
        float fg = gl[32 + base][b_ep] + bias[32 + base];
        float gg = gl[64 + base][b_ep] + bias[64 + base];
        float og = gl[96 + base][b_ep] + bias[96 + base];
        ig = 1.f / (1.f + __expf(-ig));
        fg = 1.f / (1.f + __expf(-fg));
        og = 1.f / (1.f + __expf(-og));
        gg = ftanh(gg);
        float cn = fg * c_state + ig * gg;
        cand_c[kc] = cn;
        cand_h[kc] = og * ftanh(cn);
      }
      int sel = (par[t >> 5] >> (t & 31)) & 1;
      c_state  = sel ? cand_c[1] : cand_c[0];
      float hv = sel ? cand_h[1] : cand_h[0];
      __hip_bfloat16 hb = __float2bfloat16(hv);
      hloc[jj_ep][b_ep] = *(const unsigned short*)&hb;
    }
    __syncthreads();                 // C: hloc complete; Bl/gl free next step

    // ---- publish h(t) into hs[t]: fire-and-forget bypass stores ----
    if (tid < 128) {                 // 32 ex x 4 u64 (=16 dims) per WG
      int ex = tid >> 2, part = tid & 3;
      u64 v = (u64)hloc[part * 4 + 0][ex]
            | ((u64)hloc[part * 4 + 1][ex] << 16)
            | ((u64)hloc[part * 4 + 2][ex] << 32)
            | ((u64)hloc[part * 4 + 3][ex] << 48);
      u64* dst = (u64*)hs + (size_t)t * 4096 + ex * 128 + wg * 4 + part;
      __hip_atomic_store(dst, v, __ATOMIC_RELAXED, __HIP_MEMORY_SCOPE_AGENT);
    }
    // no wait, no flag: consumers poll the data itself
  }
}

// ------------------------------------------------------------------
// logits GEMM: M=16384, N=10000, K=512, bf16 MFMA, +bias.
// Writes logits as BF16 into each row's OWN out-slot second half
// (byte off r*4*V_N + 2*V_N): f32 row r only ever overwrites its own
// bf16 -> zero cross-block aliasing. Deterministic rowpart (no atomics).
__launch_bounds__(256, 2)
__global__ void k_gemm(const __hip_bfloat16* __restrict__ hs,
                       const __hip_bfloat16* __restrict__ wout,
                       const float* __restrict__ b_out,
                       float* __restrict__ out,
                       float* __restrict__ rowpart)   // [16384][80]
{
  __shared__ __hip_bfloat16 Al[128][72];
  __shared__ __hip_bfloat16 Wt[128][72];
  __shared__ float sumLDS[2][128];         // [nq][row_local]
  const int tid = threadIdx.x;
  const int tn = blockIdx.x, tm = blockIdx.y;
  const int lane = tid & 63, wv = tid >> 6;
  const int mq = wv & 1, nq = wv >> 1;
  const int lrow = lane & 15, lk = (lane >> 4) * 8;
  f32x4 acc[4][4] = {};

  const int ar = tid >> 3, ac = (tid & 7) * 8;
  for (int k0 = 0; k0 < 512; k0 += 64) {
    __syncthreads();
    #pragma unroll
    for (int rr = 0; rr < 4; ++rr) {
      int r = ar + rr * 32;
      short8 av = *(const short8*)(hs + ((size_t)(tm * 128 + r)) * 512 + k0 + ac);
      *(short8*)&Al[r][ac] = av;
      int v = tn * 128 + r;
      short8 wvv = {};
      if (v < V_N) wvv = *(const short8*)(wout + (size_t)v * 512 + k0 + ac);
      *(short8*)&Wt[r][ac] = wvv;
    }
    __syncthreads();
    #pragma unroll
    for (int ks = 0; ks < 2; ++ks) {
      int kb = ks * 32 + lk;
      short8 af[4], bf[4];
      #pragma unroll
      for (int i = 0; i < 4; ++i) af[i] = *(const short8*)&Al[mq * 64 + i * 16 + lrow][kb];
      #pragma unroll
      for (int i = 0; i < 4; ++i) bf[i] = *(const short8*)&Wt[nq * 64 + i * 16 + lrow][kb];
      #pragma unroll
      for (int i = 0; i < 4; ++i)
        #pragma unroll
        for (int jx = 0; jx < 4; ++jx)
          acc[i][jx] = __builtin_amdgcn_mfma_f32_16x16x32_bf16(af[i], bf[jx], acc[i][jx], 0, 0, 0);
    }
  }
  const int rbase = tm * 128 + mq * 64 + (lane >> 4) * 4;
  const int cbase = tn * 128 + nq * 64 + (lane & 15);
  float esum[4][4];
  #pragma unroll
  for (int i = 0; i < 4; ++i)
    #pragma unroll
    for (int r = 0; r < 4; ++r) esum[i][r] = 0.f;

  #pragma unroll
  for (int i = 0; i < 4; ++i) {
    #pragma unroll
    for (int jx = 0; jx < 4; ++jx) {
      int col = cbase + jx * 16;
      if (col < V_N) {
        float bo = b_out[col];
        #pragma unroll
        for (int r = 0; r < 4; ++r) {
          int row = rbase + i * 16 + r;
          float lg = acc[i][jx][r] + bo;
          __hip_bfloat16* lrow16 =
            (__hip_bfloat16*)((char*)out + (size_t)row * (V_N * 4) + V_N * 2);
          lrow16[col] = __float2bfloat16(lg);
          esum[i][r] += __expf(lg);
        }
      }
    }
  }
  // reduce each (i,r) over the 16 lanes of the col group; write LDS partial
  #pragma unroll
  for (int i = 0; i < 4; ++i) {
    #pragma unroll
    for (int r = 0; r < 4; ++r) {
      float s = esum[i][r];
      s += __shfl_xor(s, 1); s += __shfl_xor(s, 2);
      s += __shfl_xor(s, 4); s += __shfl_xor(s, 8);
      if ((lane & 15) == 0)
        sumLDS[nq][mq * 64 + i * 16 + (lane >> 4) * 4 + r] = s;
    }
  }
  __syncthreads();
  if (tid < 128)   // one plain store per (row, tile): deterministic slot
    rowpart[(size_t)(tm * 128 + tid) * 80 + tn] = sumLDS[0][tid] + sumLDS[1][tid];
}

// ------------------------------------------------------------------
// fix-up: lse[r] = log(sum of 79 partials, fixed order); read own row's
// bf16 logits into registers, sync (self-overlap safety), write f32.
__launch_bounds__(256)
__global__ void k_lsm_fix(float* __restrict__ out, const float* __restrict__ rowpart) {
  const int r = blockIdx.x;
  const int tid = threadIdx.x;
  const float* rp = rowpart + (size_t)r * 80;
  float s = 0.f;
  for (int p = 0; p < 79; ++p) s += rp[p];   // same order in every thread/replay
  float lse = __logf(s);

  const f32x4* src = (const f32x4*)((const char*)out + (size_t)r * (V_N * 4) + V_N * 2);
  U128 c[5];
  #pragma unroll
  for (int i = 0; i < 5; ++i) {
    int idx = tid + i * 256;
    if (idx < 1250) c[i].f = src[idx];       // 1250 x 16B = 10000 bf16
  }
  __syncthreads();                           // all reads done before any write
  float* dst = out + (size_t)r * V_N;
  #pragma unroll
  for (int i = 0; i < 5; ++i) {
    int idx = tid + i * 256;
    if (idx < 1250) {
      const unsigned short* u = (const unsigned short*)&c[i];
      float4 lo, hi;
      lo.x = __uint_as_float((unsigned)u[0] << 16) - lse;
      lo.y = __uint_as_float((unsigned)u[1] << 16) - lse;
      lo.z = __uint_as_float((unsigned)u[2] << 16) - lse;
      lo.w = __uint_as_float((unsigned)u[3] << 16) - lse;
      hi.x = __uint_as_float((unsigned)u[4] << 16) - lse;
      hi.y = __uint_as_float((unsigned)u[5] << 16) - lse;
      hi.z = __uint_as_float((unsigned)u[6] << 16) - lse;
      hi.w = __uint_as_float((unsigned)u[7] << 16) - lse;
      *(float4*)(dst + idx * 8)     = lo;
      *(float4*)(dst + idx * 8 + 4) = hi;
    }
  }
}

// ------------------------------------------------------------------
extern "C" void kernel_launch(void* const* d_in, const int* in_sizes, int n_in,
                              void* d_out, int out_size, void* d_ws, size_t ws_size,
                              hipStream_t stream) {
  const int*   x    = (const int*)d_in[0];
  const float* tab  = (const float*)d_in[1];
  const float* Wih  = (const float*)d_in[2];
  const float* Whh  = (const float*)d_in[3];
  const float* bih  = (const float*)d_in[4];
  const float* bhh  = (const float*)d_in[5];
  const float* Wout = (const float*)d_in[6];
  const float* bout = (const float*)d_in[7];
  float* out = (float*)d_out;

  char* ws = (char*)d_ws;
  float*           rowpart = (float*)(ws + OFF_RP);
  __hip_bfloat16*  emb     = (__hip_bfloat16*)(ws + OFF_EMB);
  __hip_bfloat16*  hsbuf   = (__hip_bfloat16*)(ws + OFF_HS);
  __hip_bfloat16*  wob     = (__hip_bfloat16*)(ws + OFF_WOUT);

  // re-poison hs to the write-once sentinel every launch (replay-safe)
  hipMemsetAsync(hsbuf, 0xFF, (size_t)S_N * B_N * H_N * 2, stream);
  k_prep_emb<<<(S_N * B_N * D_E) / 256, 256, 0, stream>>>(x, tab, emb);
  k_prep_wout<<<(V_N * H_N) / 256, 256, 0, stream>>>(Wout, wob);
  k_recurrence<<<32, 512, 0, stream>>>(x, Wih, Whh, bih, bhh, emb, hsbuf);
  k_gemm<<<dim3(79, 128), 256, 0, stream>>>(hsbuf, wob, bout, out, rowpart);
  k_lsm_fix<<<16384, 256, 0, stream>>>(out, rowpart);
}

// Round 14
// 2363.040 us; speedup vs baseline: 1.1454x; 1.1454x over previous
//
#include <hip/hip_runtime.h>
#include <hip/hip_bf16.h>

typedef __attribute__((ext_vector_type(8))) short short8;
typedef __attribute__((ext_vector_type(4))) float f32x4;
typedef unsigned long long u64;

#define V_N 10000
#define D_E 128
#define H_N 512
#define B_N 32
#define S_N 512

#define SENT64 0xFFFFFFFFFFFFFFFFull   // 4x bf16 NaN: unreachable for finite h

// ---- workspace layout (bytes) ----
#define OFF_RP    0                        // rowpart: 16384 rows x 80 slots f32 = 5,242,880
#define OFF_EMB   5242880                  // S*B*D bf16 = 4,194,304
#define OFF_HS    (OFF_EMB + 4194304)      // S*B*H bf16 = 16,777,216
#define OFF_WOUT  (OFF_HS + 16777216)      // V*H bf16 = 10,240,000

// ------------------------------------------------------------------
__device__ __forceinline__ float ftanh(float x) {
  float e = __expf(-2.f * fabsf(x));          // in (0,1], overflow-safe
  float r = (1.f - e) / (1.f + e);
  return __builtin_copysignf(r, x);
}

union U128 { f32x4 f; u64 q[2]; };

// ------------------------------------------------------------------
// prep: embedding gather -> bf16 [s][b][d]
__global__ void k_prep_emb(const int* __restrict__ x, const float* __restrict__ tab,
                           __hip_bfloat16* __restrict__ emb) {
  int i = blockIdx.x * 256 + threadIdx.x;         // over S*B*D = 2,097,152
  if (i >= S_N * B_N * D_E) return;
  int d  = i & (D_E - 1);
  int sb = i >> 7;
  int b  = sb & (B_N - 1);
  int s  = sb >> 5;
  int tok = x[b * S_N + s];
  emb[i] = __float2bfloat16(tab[tok * D_E + d]);
}

// prep: W_out -> bf16
__global__ void k_prep_wout(const float* __restrict__ w, __hip_bfloat16* __restrict__ o) {
  int i = blockIdx.x * 256 + threadIdx.x;
  if (i < V_N * H_N) o[i] = __float2bfloat16(w[i]);
}

// ------------------------------------------------------------------
// persistent recurrence: 32 WGs x 512 threads (r12 structure, verbatim).
// WG w owns h-dims j = 16w..16w+15 (128 gate rows). Each wave: 16 rows x
// 32 examples over FULL K=640 (no K-split). A (weights) in registers.
// Cross-WG exchange: write-once sentinel slots in hs[t]; consumers poll
// the data itself (4 x 16-B bypass chunks/thread, masked full-drain sweep,
// linear conflict-free commit). Publish fire-and-forget.
__launch_bounds__(512, 1)
__global__ void k_recurrence(const int* __restrict__ x,
                             const float* __restrict__ W_ih, const float* __restrict__ W_hh,
                             const float* __restrict__ b_ih, const float* __restrict__ b_hh,
                             const __hip_bfloat16* __restrict__ emb,
                             __hip_bfloat16* __restrict__ hs)     // [512][32][512]
{
  __shared__ __align__(16) __hip_bfloat16 Bl[32][648];  // [example][emb128 ; h512]
  __shared__ float gl[128][34];            // [gate row][example] full-K gates
  __shared__ float bias[128];
  __shared__ unsigned short hloc[16][32];  // [jj][ex] bf16 bits of new h

  const int tid = threadIdx.x;
  const int wg  = blockIdx.x;              // 0..31
  const int lane = tid & 63, wv = tid >> 6;       // wv = wave 0..7 = row-group
  const int lrow = lane & 15, lk = (lane >> 4) * 8;
  const int b_ep = tid & 31, jj_ep = tid >> 5;    // epilogue map: 32 ex x 16 dims

  // ---- one-time: A-fragments (16 rows x full K 640) into registers ----
  short8 Afrag[20];                        // 80 VGPRs
  #pragma unroll
  for (int ks = 0; ks < 20; ++ks) {
    int lr = wv * 16 + lrow;               // local gate row 0..127
    int q = lr >> 5, kc = (lr >> 4) & 1, jj = lr & 15;
    int grow = kc * 2048 + q * 512 + wg * 16 + jj;
    int c0 = ks * 32 + lk;
    short8 a;
    #pragma unroll
    for (int e = 0; e < 8; ++e) {
      int c = c0 + e;
      float v = (c < 128) ? W_ih[(size_t)grow * 128 + c]
                          : W_hh[(size_t)grow * 512 + (c - 128)];
      __hip_bfloat16 hb = __float2bfloat16(v);
      a[e] = *(const short*)&hb;
    }
    Afrag[ks] = a;
  }
  if (tid < 128) {
    int lr = tid;
    int q = lr >> 5, kc = (lr >> 4) & 1, jj = lr & 15;
    int grow = kc * 2048 + q * 512 + wg * 16 + jj;
    bias[lr] = b_ih[grow] + b_hh[grow];
  }

  // ---- preload token parity bits (b_ep's row of x) ----
  unsigned par[16];
  #pragma unroll
  for (int w = 0; w < 16; ++w) {
    unsigned p = 0;
    for (int bb = 0; bb < 32; ++bb)
      p |= (unsigned)(x[b_ep * S_N + w * 32 + bb] & 1) << bb;
    par[w] = p;
  }

  float c_state = 0.f;                         // carry for (b_ep, jj_ep)

  for (int t = 0; t < S_N; ++t) {
    // ---- stage emb_t: 1 x 16B cached load/thread (512 chunks) ----
    {
      const f32x4* e16 = (const f32x4*)(emb + (size_t)t * B_N * D_E);
      int ex = tid >> 4, col = tid & 15;
      *(f32x4*)((char*)&Bl[0][0] + ex * 1296 + col * 16) = e16[tid];
    }
    // ---- stage h_prev: masked 16-B sentinel poll, 4 chunks/thread ----
    if (t == 0) {
      for (int i = tid; i < 4096; i += 512) {
        int b = i >> 7, hh = i & 127;
        *(u64*)&Bl[b][128 + hh * 4] = 0ull;
      }
    } else {
      const char* srcb = (const char*)hs + (size_t)(t - 1) * 32768;
      U128 buf[4];
      unsigned pend = 0xFu;
      while (pend) {
        #pragma unroll
        for (int c = 0; c < 4; ++c)
          if (pend & (1u << c))
            asm volatile("global_load_dwordx4 %0, %1, off sc0 sc1"
                         : "=v"(buf[c].f) : "v"(srcb + (c * 8192 + tid * 16)) : "memory");
        asm volatile("s_waitcnt vmcnt(0)" ::: "memory");
        __builtin_amdgcn_sched_barrier(0);
        #pragma unroll
        for (int c = 0; c < 4; ++c)
          if ((pend & (1u << c)) && buf[c].q[0] != SENT64 && buf[c].q[1] != SENT64) {
            int ci = c * 512 + tid;        // chunk 0..2047
            *(f32x4*)((char*)&Bl[0][0] + (ci >> 6) * 1296 + 256 + (ci & 63) * 16) = buf[c].f;
            pend &= ~(1u << c);
          }
      }
    }
    __syncthreads();                 // A: B ready

    // ---- MFMA: wave wv: rows [wv*16,+16) x 32 ex over full K=640 ----
    {
      f32x4 acc0 = {0.f,0.f,0.f,0.f}, acc1 = {0.f,0.f,0.f,0.f};
      #pragma unroll
      for (int ks = 0; ks < 20; ++ks) {
        int cb = (ks * 32 + lk) * 2;       // byte offset in a row
        short8 b0 = *(const short8*)((const char*)&Bl[0][0] + lrow * 1296 + cb);
        short8 b1 = *(const short8*)((const char*)&Bl[0][0] + (16 + lrow) * 1296 + cb);
        acc0 = __builtin_amdgcn_mfma_f32_16x16x32_bf16(Afrag[ks], b0, acc0, 0, 0, 0);
        acc1 = __builtin_amdgcn_mfma_f32_16x16x32_bf16(Afrag[ks], b1, acc1, 0, 0, 0);
      }
      int r0 = wv * 16 + (lane >> 4) * 4;
      int cb0 = lane & 15;
      #pragma unroll
      for (int r = 0; r < 4; ++r) {
        gl[r0 + r][cb0]      = acc0[r];
        gl[r0 + r][16 + cb0] = acc1[r];
      }
    }
    __syncthreads();                 // B: all gates ready (full K, no partials)

    // ---- epilogue: thread <-> (b_ep, jj_ep in 0..15) ----
    {
      float cand_c[2], cand_h[2];
      #pragma unroll
      for (int kc = 0; kc < 2; ++kc) {
        int base = kc * 16 + jj_ep;
        float ig = gl[base][b_ep]      + bias[base];
        float fg = gl[32 + base][b_ep] + bias[32 + base];
        float gg = gl[64 + base][b_ep] + bias[64 + base];
        float og = gl[96 + base][b_ep] + bias[96 + base];
        ig = 1.f / (1.f + __expf(-ig));
        fg = 1.f / (1.f + __expf(-fg));
        og = 1.f / (1.f + __expf(-og));
        gg = ftanh(gg);
        float cn = fg * c_state + ig * gg;
        cand_c[kc] = cn;
        cand_h[kc] = og * ftanh(cn);
      }
      int sel = (par[t >> 5] >> (t & 31)) & 1;
      c_state  = sel ? cand_c[1] : cand_c[0];
      float hv = sel ? cand_h[1] : cand_h[0];
      __hip_bfloat16 hb = __float2bfloat16(hv);
      hloc[jj_ep][b_ep] = *(const unsigned short*)&hb;
    }
    __syncthreads();                 // C: hloc complete; Bl/gl free next step

    // ---- publish h(t) into hs[t]: fire-and-forget bypass stores ----
    if (tid < 128) {                 // 32 ex x 4 u64 (=16 dims) per WG
      int ex = tid >> 2, part = tid & 3;
      u64 v = (u64)hloc[part * 4 + 0][ex]
            | ((u64)hloc[part * 4 + 1][ex] << 16)
            | ((u64)hloc[part * 4 + 2][ex] << 32)
            | ((u64)hloc[part * 4 + 3][ex] << 48);
      u64* dst = (u64*)hs + (size_t)t * 4096 + ex * 128 + wg * 4 + part;
      __hip_atomic_store(dst, v, __ATOMIC_RELAXED, __HIP_MEMORY_SCOPE_AGENT);
    }
    // no wait, no flag: consumers poll the data itself
  }
}

// ------------------------------------------------------------------
// logits GEMM: M=16384, N=10000, K=512, bf16 MFMA, +bias.
// Writes logits as BF16 into each row's OWN out-slot second half
// (byte off r*4*V_N + 2*V_N): f32 row r only ever overwrites its own
// bf16 -> zero cross-block aliasing. Deterministic rowpart (no atomics).
__launch_bounds__(256, 2)
__global__ void k_gemm(const __hip_bfloat16* __restrict__ hs,
                       const __hip_bfloat16* __restrict__ wout,
                       const float* __restrict__ b_out,
                       float* __restrict__ out,
                       float* __restrict__ rowpart)   // [16384][80]
{
  __shared__ __hip_bfloat16 Al[128][72];
  __shared__ __hip_bfloat16 Wt[128][72];
  __shared__ float sumLDS[2][128];         // [nq][row_local]
  const int tid = threadIdx.x;
  const int tn = blockIdx.x, tm = blockIdx.y;
  const int lane = tid & 63, wv = tid >> 6;
  const int mq = wv & 1, nq = wv >> 1;
  const int lrow = lane & 15, lk = (lane >> 4) * 8;
  f32x4 acc[4][4] = {};

  const int ar = tid >> 3, ac = (tid & 7) * 8;
  for (int k0 = 0; k0 < 512; k0 += 64) {
    __syncthreads();
    #pragma unroll
    for (int rr = 0; rr < 4; ++rr) {
      int r = ar + rr * 32;
      short8 av = *(const short8*)(hs + ((size_t)(tm * 128 + r)) * 512 + k0 + ac);
      *(short8*)&Al[r][ac] = av;
      int v = tn * 128 + r;
      short8 wvv = {};
      if (v < V_N) wvv = *(const short8*)(wout + (size_t)v * 512 + k0 + ac);
      *(short8*)&Wt[r][ac] = wvv;
    }
    __syncthreads();
    #pragma unroll
    for (int ks = 0; ks < 2; ++ks) {
      int kb = ks * 32 + lk;
      short8 af[4], bf[4];
      #pragma unroll
      for (int i = 0; i < 4; ++i) af[i] = *(const short8*)&Al[mq * 64 + i * 16 + lrow][kb];
      #pragma unroll
      for (int i = 0; i < 4; ++i) bf[i] = *(const short8*)&Wt[nq * 64 + i * 16 + lrow][kb];
      #pragma unroll
      for (int i = 0; i < 4; ++i)
        #pragma unroll
        for (int jx = 0; jx < 4; ++jx)
          acc[i][jx] = __builtin_amdgcn_mfma_f32_16x16x32_bf16(af[i], bf[jx], acc[i][jx], 0, 0, 0);
    }
  }
  const int rbase = tm * 128 + mq * 64 + (lane >> 4) * 4;
  const int cbase = tn * 128 + nq * 64 + (lane & 15);
  float esum[4][4];
  #pragma unroll
  for (int i = 0; i < 4; ++i)
    #pragma unroll
    for (int r = 0; r < 4; ++r) esum[i][r] = 0.f;

  #pragma unroll
  for (int i = 0; i < 4; ++i) {
    #pragma unroll
    for (int jx = 0; jx < 4; ++jx) {
      int col = cbase + jx * 16;
      if (col < V_N) {
        float bo = b_out[col];
        #pragma unroll
        for (int r = 0; r < 4; ++r) {
          int row = rbase + i * 16 + r;
          float lg = acc[i][jx][r] + bo;
          __hip_bfloat16* lrow16 =
            (__hip_bfloat16*)((char*)out + (size_t)row * (V_N * 4) + V_N * 2);
          lrow16[col] = __float2bfloat16(lg);
          esum[i][r] += __expf(lg);
        }
      }
    }
  }
  // reduce each (i,r) over the 16 lanes of the col group; write LDS partial
  #pragma unroll
  for (int i = 0; i < 4; ++i) {
    #pragma unroll
    for (int r = 0; r < 4; ++r) {
      float s = esum[i][r];
      s += __shfl_xor(s, 1); s += __shfl_xor(s, 2);
      s += __shfl_xor(s, 4); s += __shfl_xor(s, 8);
      if ((lane & 15) == 0)
        sumLDS[nq][mq * 64 + i * 16 + (lane >> 4) * 4 + r] = s;
    }
  }
  __syncthreads();
  if (tid < 128)   // one plain store per (row, tile): deterministic slot
    rowpart[(size_t)(tm * 128 + tid) * 80 + tn] = sumLDS[0][tid] + sumLDS[1][tid];
}

// ------------------------------------------------------------------
// fix-up: lse[r] = log(sum of 79 partials, fixed order); read own row's
// bf16 logits into registers, sync (self-overlap safety), write f32.
__launch_bounds__(256)
__global__ void k_lsm_fix(float* __restrict__ out, const float* __restrict__ rowpart) {
  const int r = blockIdx.x;
  const int tid = threadIdx.x;
  const float* rp = rowpart + (size_t)r * 80;
  float s = 0.f;
  for (int p = 0; p < 79; ++p) s += rp[p];   // same order in every thread/replay
  float lse = __logf(s);

  const f32x4* src = (const f32x4*)((const char*)out + (size_t)r * (V_N * 4) + V_N * 2);
  U128 c[5];
  #pragma unroll
  for (int i = 0; i < 5; ++i) {
    int idx = tid + i * 256;
    if (idx < 1250) c[i].f = src[idx];       // 1250 x 16B = 10000 bf16
  }
  __syncthreads();                           // all reads done before any write
  float* dst = out + (size_t)r * V_N;
  #pragma unroll
  for (int i = 0; i < 5; ++i) {
    int idx = tid + i * 256;
    if (idx < 1250) {
      const unsigned short* u = (const unsigned short*)&c[i];
      float4 lo, hi;
      lo.x = __uint_as_float((unsigned)u[0] << 16) - lse;
      lo.y = __uint_as_float((unsigned)u[1] << 16) - lse;
      lo.z = __uint_as_float((unsigned)u[2] << 16) - lse;
      lo.w = __uint_as_float((unsigned)u[3] << 16) - lse;
      hi.x = __uint_as_float((unsigned)u[4] << 16) - lse;
      hi.y = __uint_as_float((unsigned)u[5] << 16) - lse;
      hi.z = __uint_as_float((unsigned)u[6] << 16) - lse;
      hi.w = __uint_as_float((unsigned)u[7] << 16) - lse;
      *(float4*)(dst + idx * 8)     = lo;
      *(float4*)(dst + idx * 8 + 4) = hi;
    }
  }
}

// ------------------------------------------------------------------
extern "C" void kernel_launch(void* const* d_in, const int* in_sizes, int n_in,
                              void* d_out, int out_size, void* d_ws, size_t ws_size,
                              hipStream_t stream) {
  const int*   x    = (const int*)d_in[0];
  const float* tab  = (const float*)d_in[1];
  const float* Wih  = (const float*)d_in[2];
  const float* Whh  = (const float*)d_in[3];
  const float* bih  = (const float*)d_in[4];
  const float* bhh  = (const float*)d_in[5];
  const float* Wout = (const float*)d_in[6];
  const float* bout = (const float*)d_in[7];
  float* out = (float*)d_out;

  char* ws = (char*)d_ws;
  float*           rowpart = (float*)(ws + OFF_RP);
  __hip_bfloat16*  emb     = (__hip_bfloat16*)(ws + OFF_EMB);
  __hip_bfloat16*  hsbuf   = (__hip_bfloat16*)(ws + OFF_HS);
  __hip_bfloat16*  wob     = (__hip_bfloat16*)(ws + OFF_WOUT);

  // re-poison hs to the write-once sentinel every launch (replay-safe)
  hipMemsetAsync(hsbuf, 0xFF, (size_t)S_N * B_N * H_N * 2, stream);
  k_prep_emb<<<(S_N * B_N * D_E) / 256, 256, 0, stream>>>(x, tab, emb);
  k_prep_wout<<<(V_N * H_N) / 256, 256, 0, stream>>>(Wout, wob);
  k_recurrence<<<32, 512, 0, stream>>>(x, Wih, Whh, bih, bhh, emb, hsbuf);
  k_gemm<<<dim3(79, 128), 256, 0, stream>>>(hsbuf, wob, bout, out, rowpart);
  k_lsm_fix<<<16384, 256, 0, stream>>>(out, rowpart);
}

// Round 15
// 2288.352 us; speedup vs baseline: 1.1828x; 1.0326x over previous
//
#include <hip/hip_runtime.h>
#include <hip/hip_bf16.h>

typedef __attribute__((ext_vector_type(8))) short short8;
typedef __attribute__((ext_vector_type(4))) float f32x4;
typedef unsigned long long u64;

#define V_N 10000
#define D_E 128
#define H_N 512
#define B_N 32
#define S_N 512

#define SENT64 0xFFFFFFFFFFFFFFFFull   // 4x bf16 NaN: unreachable for finite h

// ---- workspace layout (bytes) ----
#define OFF_RP    0                        // rowpart: 16384 rows x 80 slots f32 = 5,242,880
#define OFF_EMB   5242880                  // S*B*D bf16 = 4,194,304
#define OFF_HS    (OFF_EMB + 4194304)      // S*B*H bf16 = 16,777,216
#define OFF_WOUT  (OFF_HS + 16777216)      // V*H bf16 = 10,240,000

// ------------------------------------------------------------------
__device__ __forceinline__ float ftanh(float x) {
  float e = __expf(-2.f * fabsf(x));          // in (0,1], overflow-safe
  float r = (1.f - e) / (1.f + e);
  return __builtin_copysignf(r, x);
}

union U128 { f32x4 f; u64 q[2]; };

// ------------------------------------------------------------------
// prep: embedding gather -> bf16 [s][b][d]
__global__ void k_prep_emb(const int* __restrict__ x, const float* __restrict__ tab,
                           __hip_bfloat16* __restrict__ emb) {
  int i = blockIdx.x * 256 + threadIdx.x;         // over S*B*D = 2,097,152
  if (i >= S_N * B_N * D_E) return;
  int d  = i & (D_E - 1);
  int sb = i >> 7;
  int b  = sb & (B_N - 1);
  int s  = sb >> 5;
  int tok = x[b * S_N + s];
  emb[i] = __float2bfloat16(tab[tok * D_E + d]);
}

// prep: W_out -> bf16
__global__ void k_prep_wout(const float* __restrict__ w, __hip_bfloat16* __restrict__ o) {
  int i = blockIdx.x * 256 + threadIdx.x;
  if (i < V_N * H_N) o[i] = __float2bfloat16(w[i]);
}

// ------------------------------------------------------------------
// persistent recurrence: 32 WGs x 512 threads.
// REGISTER EPILOGUE: wave wv's 16 A-rows are remapped so the wave owns all
// 4 gates x both cells for h-dims jj = wv*2, wv*2+1:
//   row (0..15) -> kc = row>>3, jp = (row>>2)&1, gate = row&3
// After MFMA, lane (g=l>>4, c=l&15) holds i,f,g,o (acc regs r=0..3) for
// (cell kc=g>>1, dim jj=wv*2+(g&1), b=c / c+16). LSTM pointwise math stays
// in registers; the two cells exchange candidates with one shfl_xor(32).
// No gate-LDS (gl), no sync-B. Poll/publish protocol unchanged from r14.
__launch_bounds__(512, 1)
__global__ void k_recurrence(const int* __restrict__ x,
                             const float* __restrict__ W_ih, const float* __restrict__ W_hh,
                             const float* __restrict__ b_ih, const float* __restrict__ b_hh,
                             const __hip_bfloat16* __restrict__ emb,
                             __hip_bfloat16* __restrict__ hs)     // [512][32][512]
{
  __shared__ __align__(16) __hip_bfloat16 Bl[32][648];  // [example][emb128 ; h512]
  __shared__ unsigned short hloc[16][32];  // [jj][ex] bf16 bits of new h

  const int tid = threadIdx.x;
  const int wg  = blockIdx.x;              // 0..31
  const int lane = tid & 63, wv = tid >> 6;       // wv = wave 0..7
  const int lrow = lane & 15, lk = (lane >> 4) * 8;

  // ---- one-time: A-fragments (16 remapped rows x full K 640) ----
  short8 Afrag[20];                        // 80 VGPRs
  {
    int kcA = lrow >> 3, jpA = (lrow >> 2) & 1, gateA = lrow & 3;
    int grow = kcA * 2048 + gateA * 512 + wg * 16 + wv * 2 + jpA;
    #pragma unroll
    for (int ks = 0; ks < 20; ++ks) {
      int c0 = ks * 32 + lk;
      short8 a;
      #pragma unroll
      for (int e = 0; e < 8; ++e) {
        int c = c0 + e;
        float v = (c < 128) ? W_ih[(size_t)grow * 128 + c]
                            : W_hh[(size_t)grow * 512 + (c - 128)];
        __hip_bfloat16 hb = __float2bfloat16(v);
        a[e] = *(const short*)&hb;
      }
      Afrag[ks] = a;
    }
  }

  // ---- output mapping: lane (g=l>>4, c=l&15) ----
  const int g  = lane >> 4;
  const int kc = g >> 1, jp = g & 1;
  const int jj = wv * 2 + jp;
  float bias4[4];
  #pragma unroll
  for (int r = 0; r < 4; ++r) {
    int gr = kc * 2048 + r * 512 + wg * 16 + jj;
    bias4[r] = b_ih[gr] + b_hh[gr];
  }

  // ---- token parity bits for this lane's two examples ----
  const int bA = lane & 15, bB = 16 + bA;
  unsigned parA[16], parB[16];
  #pragma unroll
  for (int w = 0; w < 16; ++w) {
    unsigned pa = 0, pb = 0;
    for (int bb = 0; bb < 32; ++bb) {
      pa |= (unsigned)(x[bA * S_N + w * 32 + bb] & 1) << bb;
      pb |= (unsigned)(x[bB * S_N + w * 32 + bb] & 1) << bb;
    }
    parA[w] = pa; parB[w] = pb;
  }

  float csA = 0.f, csB = 0.f;              // c_state for (jj, bA) / (jj, bB)

  for (int t = 0; t < S_N; ++t) {
    // ---- stage emb_t: 1 x 16B cached load/thread (512 chunks) ----
    {
      const f32x4* e16 = (const f32x4*)(emb + (size_t)t * B_N * D_E);
      int ex = tid >> 4, col = tid & 15;
      *(f32x4*)((char*)&Bl[0][0] + ex * 1296 + col * 16) = e16[tid];
    }
    // ---- stage h_prev: masked 16-B sentinel poll, 4 chunks/thread ----
    if (t == 0) {
      for (int i = tid; i < 4096; i += 512) {
        int b = i >> 7, hh = i & 127;
        *(u64*)&Bl[b][128 + hh * 4] = 0ull;
      }
    } else {
      const char* srcb = (const char*)hs + (size_t)(t - 1) * 32768;
      U128 buf[4];
      unsigned pend = 0xFu;
      while (pend) {
        #pragma unroll
        for (int c = 0; c < 4; ++c)
          if (pend & (1u << c))
            asm volatile("global_load_dwordx4 %0, %1, off sc0 sc1"
                         : "=v"(buf[c].f) : "v"(srcb + (c * 8192 + tid * 16)) : "memory");
        asm volatile("s_waitcnt vmcnt(0)" ::: "memory");
        __builtin_amdgcn_sched_barrier(0);
        #pragma unroll
        for (int c = 0; c < 4; ++c)
          if ((pend & (1u << c)) && buf[c].q[0] != SENT64 && buf[c].q[1] != SENT64) {
            int ci = c * 512 + tid;        // chunk 0..2047
            *(f32x4*)((char*)&Bl[0][0] + (ci >> 6) * 1296 + 256 + (ci & 63) * 16) = buf[c].f;
            pend &= ~(1u << c);
          }
      }
    }
    __syncthreads();                 // A: B ready

    // ---- MFMA: wave wv, remapped 16 rows x 32 ex over full K=640 ----
    f32x4 acc0 = {0.f,0.f,0.f,0.f}, acc1 = {0.f,0.f,0.f,0.f};
    #pragma unroll
    for (int ks = 0; ks < 20; ++ks) {
      int cb = (ks * 32 + lk) * 2;         // byte offset in a row
      short8 b0 = *(const short8*)((const char*)&Bl[0][0] + lrow * 1296 + cb);
      short8 b1 = *(const short8*)((const char*)&Bl[0][0] + (16 + lrow) * 1296 + cb);
      acc0 = __builtin_amdgcn_mfma_f32_16x16x32_bf16(Afrag[ks], b0, acc0, 0, 0, 0);
      acc1 = __builtin_amdgcn_mfma_f32_16x16x32_bf16(Afrag[ks], b1, acc1, 0, 0, 0);
    }

    // ---- register epilogue: own-cell candidates + shfl_xor(32) swap ----
    {
      float iA = 1.f / (1.f + __expf(-(acc0[0] + bias4[0])));
      float fA = 1.f / (1.f + __expf(-(acc0[1] + bias4[1])));
      float gA = ftanh(acc0[2] + bias4[2]);
      float oA = 1.f / (1.f + __expf(-(acc0[3] + bias4[3])));
      float cnA = fA * csA + iA * gA;
      float hnA = oA * ftanh(cnA);

      float iB = 1.f / (1.f + __expf(-(acc1[0] + bias4[0])));
      float fB = 1.f / (1.f + __expf(-(acc1[1] + bias4[1])));
      float gB = ftanh(acc1[2] + bias4[2]);
      float oB = 1.f / (1.f + __expf(-(acc1[3] + bias4[3])));
      float cnB = fB * csB + iB * gB;
      float hnB = oB * ftanh(cnB);

      float pcA = __shfl_xor(cnA, 32), phA = __shfl_xor(hnA, 32);
      float pcB = __shfl_xor(cnB, 32), phB = __shfl_xor(hnB, 32);

      float c0A = kc ? pcA : cnA, c1A = kc ? cnA : pcA;
      float h0A = kc ? phA : hnA, h1A = kc ? hnA : phA;
      float c0B = kc ? pcB : cnB, c1B = kc ? cnB : pcB;
      float h0B = kc ? phB : hnB, h1B = kc ? hnB : phB;

      int selA = (parA[t >> 5] >> (t & 31)) & 1;
      int selB = (parB[t >> 5] >> (t & 31)) & 1;
      csA = selA ? c1A : c0A;  float hA = selA ? h1A : h0A;
      csB = selB ? c1B : c0B;  float hB = selB ? h1B : h0B;

      if (kc == 0) {
        __hip_bfloat16 ha = __float2bfloat16(hA);
        __hip_bfloat16 hb2 = __float2bfloat16(hB);
        hloc[jj][bA] = *(const unsigned short*)&ha;
        hloc[jj][bB] = *(const unsigned short*)&hb2;
      }
    }
    __syncthreads();                 // C: hloc ready; all Bl reads done

    // ---- publish h(t) into hs[t]: fire-and-forget bypass stores ----
    if (tid < 128) {                 // 32 ex x 4 u64 (=16 dims) per WG
      int ex = tid >> 2, part = tid & 3;
      u64 v = (u64)hloc[part * 4 + 0][ex]
            | ((u64)hloc[part * 4 + 1][ex] << 16)
            | ((u64)hloc[part * 4 + 2][ex] << 32)
            | ((u64)hloc[part * 4 + 3][ex] << 48);
      u64* dst = (u64*)hs + (size_t)t * 4096 + ex * 128 + wg * 4 + part;
      __hip_atomic_store(dst, v, __ATOMIC_RELAXED, __HIP_MEMORY_SCOPE_AGENT);
    }
    // no wait, no flag: consumers poll the data itself
  }
}

// ------------------------------------------------------------------
// logits GEMM: M=16384, N=10000, K=512, bf16 MFMA, +bias.
// Writes logits as BF16 into each row's OWN out-slot second half
// (byte off r*4*V_N + 2*V_N): f32 row r only ever overwrites its own
// bf16 -> zero cross-block aliasing. Deterministic rowpart (no atomics).
__launch_bounds__(256, 2)
__global__ void k_gemm(const __hip_bfloat16* __restrict__ hs,
                       const __hip_bfloat16* __restrict__ wout,
                       const float* __restrict__ b_out,
                       float* __restrict__ out,
                       float* __restrict__ rowpart)   // [16384][80]
{
  __shared__ __hip_bfloat16 Al[128][72];
  __shared__ __hip_bfloat16 Wt[128][72];
  __shared__ float sumLDS[2][128];         // [nq][row_local]
  const int tid = threadIdx.x;
  const int tn = blockIdx.x, tm = blockIdx.y;
  const int lane = tid & 63, wv = tid >> 6;
  const int mq = wv & 1, nq = wv >> 1;
  const int lrow = lane & 15, lk = (lane >> 4) * 8;
  f32x4 acc[4][4] = {};

  const int ar = tid >> 3, ac = (tid & 7) * 8;
  for (int k0 = 0; k0 < 512; k0 += 64) {
    __syncthreads();
    #pragma unroll
    for (int rr = 0; rr < 4; ++rr) {
      int r = ar + rr * 32;
      short8 av = *(const short8*)(hs + ((size_t)(tm * 128 + r)) * 512 + k0 + ac);
      *(short8*)&Al[r][ac] = av;
      int v = tn * 128 + r;
      short8 wvv = {};
      if (v < V_N) wvv = *(const short8*)(wout + (size_t)v * 512 + k0 + ac);
      *(short8*)&Wt[r][ac] = wvv;
    }
    __syncthreads();
    #pragma unroll
    for (int ks = 0; ks < 2; ++ks) {
      int kb = ks * 32 + lk;
      short8 af[4], bf[4];
      #pragma unroll
      for (int i = 0; i < 4; ++i) af[i] = *(const short8*)&Al[mq * 64 + i * 16 + lrow][kb];
      #pragma unroll
      for (int i = 0; i < 4; ++i) bf[i] = *(const short8*)&Wt[nq * 64 + i * 16 + lrow][kb];
      #pragma unroll
      for (int i = 0; i < 4; ++i)
        #pragma unroll
        for (int jx = 0; jx < 4; ++jx)
          acc[i][jx] = __builtin_amdgcn_mfma_f32_16x16x32_bf16(af[i], bf[jx], acc[i][jx], 0, 0, 0);
    }
  }
  const int rbase = tm * 128 + mq * 64 + (lane >> 4) * 4;
  const int cbase = tn * 128 + nq * 64 + (lane & 15);
  float esum[4][4];
  #pragma unroll
  for (int i = 0; i < 4; ++i)
    #pragma unroll
    for (int r = 0; r < 4; ++r) esum[i][r] = 0.f;

  #pragma unroll
  for (int i = 0; i < 4; ++i) {
    #pragma unroll
    for (int jx = 0; jx < 4; ++jx) {
      int col = cbase + jx * 16;
      if (col < V_N) {
        float bo = b_out[col];
        #pragma unroll
        for (int r = 0; r < 4; ++r) {
          int row = rbase + i * 16 + r;
          float lg = acc[i][jx][r] + bo;
          __hip_bfloat16* lrow16 =
            (__hip_bfloat16*)((char*)out + (size_t)row * (V_N * 4) + V_N * 2);
          lrow16[col] = __float2bfloat16(lg);
          esum[i][r] += __expf(lg);
        }
      }
    }
  }
  // reduce each (i,r) over the 16 lanes of the col group; write LDS partial
  #pragma unroll
  for (int i = 0; i < 4; ++i) {
    #pragma unroll
    for (int r = 0; r < 4; ++r) {
      float s = esum[i][r];
      s += __shfl_xor(s, 1); s += __shfl_xor(s, 2);
      s += __shfl_xor(s, 4); s += __shfl_xor(s, 8);
      if ((lane & 15) == 0)
        sumLDS[nq][mq * 64 + i * 16 + (lane >> 4) * 4 + r] = s;
    }
  }
  __syncthreads();
  if (tid < 128)   // one plain store per (row, tile): deterministic slot
    rowpart[(size_t)(tm * 128 + tid) * 80 + tn] = sumLDS[0][tid] + sumLDS[1][tid];
}

// ------------------------------------------------------------------
// fix-up: lse[r] = log(sum of 79 partials, fixed order); read own row's
// bf16 logits into registers, sync (self-overlap safety), write f32.
__launch_bounds__(256)
__global__ void k_lsm_fix(float* __restrict__ out, const float* __restrict__ rowpart) {
  const int r = blockIdx.x;
  const int tid = threadIdx.x;
  const float* rp = rowpart + (size_t)r * 80;
  float s = 0.f;
  for (int p = 0; p < 79; ++p) s += rp[p];   // same order in every thread/replay
  float lse = __logf(s);

  const f32x4* src = (const f32x4*)((const char*)out + (size_t)r * (V_N * 4) + V_N * 2);
  U128 c[5];
  #pragma unroll
  for (int i = 0; i < 5; ++i) {
    int idx = tid + i * 256;
    if (idx < 1250) c[i].f = src[idx];       // 1250 x 16B = 10000 bf16
  }
  __syncthreads();                           // all reads done before any write
  float* dst = out + (size_t)r * V_N;
  #pragma unroll
  for (int i = 0; i < 5; ++i) {
    int idx = tid + i * 256;
    if (idx < 1250) {
      const unsigned short* u = (const unsigned short*)&c[i];
      float4 lo, hi;
      lo.x = __uint_as_float((unsigned)u[0] << 16) - lse;
      lo.y = __uint_as_float((unsigned)u[1] << 16) - lse;
      lo.z = __uint_as_float((unsigned)u[2] << 16) - lse;
      lo.w = __uint_as_float((unsigned)u[3] << 16) - lse;
      hi.x = __uint_as_float((unsigned)u[4] << 16) - lse;
      hi.y = __uint_as_float((unsigned)u[5] << 16) - lse;
      hi.z = __uint_as_float((unsigned)u[6] << 16) - lse;
      hi.w = __uint_as_float((unsigned)u[7] << 16) - lse;
      *(float4*)(dst + idx * 8)     = lo;
      *(float4*)(dst + idx * 8 + 4) = hi;
    }
  }
}

// ------------------------------------------------------------------
extern "C" void kernel_launch(void* const* d_in, const int* in_sizes, int n_in,
                              void* d_out, int out_size, void* d_ws, size_t ws_size,
                              hipStream_t stream) {
  const int*   x    = (const int*)d_in[0];
  const float* tab  = (const float*)d_in[1];
  const float* Wih  = (const float*)d_in[2];
  const float* Whh  = (const float*)d_in[3];
  const float* bih  = (const float*)d_in[4];
  const float* bhh  = (const float*)d_in[5];
  const float* Wout = (const float*)d_in[6];
  const float* bout = (const float*)d_in[7];
  float* out = (float*)d_out;

  char* ws = (char*)d_ws;
  float*           rowpart = (float*)(ws + OFF_RP);
  __hip_bfloat16*  emb     = (__hip_bfloat16*)(ws + OFF_EMB);
  __hip_bfloat16*  hsbuf   = (__hip_bfloat16*)(ws + OFF_HS);
  __hip_bfloat16*  wob     = (__hip_bfloat16*)(ws + OFF_WOUT);

  // re-poison hs to the write-once sentinel every launch (replay-safe)
  hipMemsetAsync(hsbuf, 0xFF, (size_t)S_N * B_N * H_N * 2, stream);
  k_prep_emb<<<(S_N * B_N * D_E) / 256, 256, 0, stream>>>(x, tab, emb);
  k_prep_wout<<<(V_N * H_N) / 256, 256, 0, stream>>>(Wout, wob);
  k_recurrence<<<32, 512, 0, stream>>>(x, Wih, Whh, bih, bhh, emb, hsbuf);
  k_gemm<<<dim3(79, 128), 256, 0, stream>>>(hsbuf, wob, bout, out, rowpart);
  k_lsm_fix<<<16384, 256, 0, stream>>>(out, rowpart);
}

// Round 16
// 2279.448 us; speedup vs baseline: 1.1874x; 1.0039x over previous
//
#include <hip/hip_runtime.h>
#include <hip/hip_bf16.h>

typedef __attribute__((ext_vector_type(8))) short short8;
typedef __attribute__((ext_vector_type(4))) float f32x4;
typedef unsigned long long u64;

#define V_N 10000
#define V_PAD 10112                      // 79*128, padded for gload_lds staging
#define D_E 128
#define H_N 512
#define B_N 32
#define S_N 512

#define SENT64 0xFFFFFFFFFFFFFFFFull   // bf16 NaN pattern: unreachable for finite h
#define SENT32 0xFFFFFFFFu

// ---- workspace layout (bytes) ----
#define OFF_RP    0                        // rowpart: 16384 x 80 f32 = 5,242,880
#define OFF_EMB   5242880                  // S*B*D bf16 = 4,194,304
#define OFF_HS    (OFF_EMB + 4194304)      // S*B*H bf16 = 16,777,216
#define OFF_WOUT  (OFF_HS + 16777216)      // V_PAD*H bf16 = 10,354,688

typedef __attribute__((address_space(1))) const unsigned gas_u32;
typedef __attribute__((address_space(3))) unsigned las_u32;

// ------------------------------------------------------------------
__device__ __forceinline__ float ftanh(float x) {
  float e = __expf(-2.f * fabsf(x));          // in (0,1], overflow-safe
  float r = (1.f - e) / (1.f + e);
  return __builtin_copysignf(r, x);
}

union U128 { f32x4 f; u64 q[2]; unsigned w[4]; };

// ------------------------------------------------------------------
// prep: embedding gather -> bf16 [s][b][d]
__global__ void k_prep_emb(const int* __restrict__ x, const float* __restrict__ tab,
                           __hip_bfloat16* __restrict__ emb) {
  int i = blockIdx.x * 256 + threadIdx.x;         // over S*B*D = 2,097,152
  if (i >= S_N * B_N * D_E) return;
  int d  = i & (D_E - 1);
  int sb = i >> 7;
  int b  = sb & (B_N - 1);
  int s  = sb >> 5;
  int tok = x[b * S_N + s];
  emb[i] = __float2bfloat16(tab[tok * D_E + d]);
}

// prep: W_out -> bf16, zero-padded to V_PAD rows
__global__ void k_prep_wout(const float* __restrict__ w, __hip_bfloat16* __restrict__ o) {
  int i = blockIdx.x * 256 + threadIdx.x;         // over V_PAD*H
  if (i >= V_PAD * H_N) return;
  o[i] = (i < V_N * H_N) ? __float2bfloat16(w[i]) : __float2bfloat16(0.f);
}

// ------------------------------------------------------------------
// persistent recurrence: 32 WGs x 512 threads, register epilogue (r15).
// NEW: per-wave EARLY publish -- each wave owns h-dims jj=wv*2,wv*2+1;
// after its register epilogue it packs (jj,jj+1) per example into a u32
// (one shfl_xor(16)) and bypass-stores immediately (before syncC).
// hloc eliminated. Consumers poll 16-B chunks but check sentinel per-u32
// (different waves fill different u32s of a chunk at different times).
__launch_bounds__(512, 1)
__global__ void k_recurrence(const int* __restrict__ x,
                             const float* __restrict__ W_ih, const float* __restrict__ W_hh,
                             const float* __restrict__ b_ih, const float* __restrict__ b_hh,
                             const __hip_bfloat16* __restrict__ emb,
                             __hip_bfloat16* __restrict__ hs)     // [512][32][512]
{
  __shared__ __align__(16) __hip_bfloat16 Bl[32][648];  // [example][emb128 ; h512]

  const int tid = threadIdx.x;
  const int wg  = blockIdx.x;              // 0..31
  const int lane = tid & 63, wv = tid >> 6;       // wv = wave 0..7
  const int lrow = lane & 15, lk = (lane >> 4) * 8;

  // ---- one-time: A-fragments (16 remapped rows x full K 640) ----
  short8 Afrag[20];                        // 80 VGPRs
  {
    int kcA = lrow >> 3, jpA = (lrow >> 2) & 1, gateA = lrow & 3;
    int grow = kcA * 2048 + gateA * 512 + wg * 16 + wv * 2 + jpA;
    #pragma unroll
    for (int ks = 0; ks < 20; ++ks) {
      int c0 = ks * 32 + lk;
      short8 a;
      #pragma unroll
      for (int e = 0; e < 8; ++e) {
        int c = c0 + e;
        float v = (c < 128) ? W_ih[(size_t)grow * 128 + c]
                            : W_hh[(size_t)grow * 512 + (c - 128)];
        __hip_bfloat16 hb = __float2bfloat16(v);
        a[e] = *(const short*)&hb;
      }
      Afrag[ks] = a;
    }
  }

  // ---- output mapping: lane (g=l>>4, c=l&15) ----
  const int g  = lane >> 4;
  const int kc = g >> 1, jp = g & 1;
  const int jj = wv * 2 + jp;
  float bias4[4];
  #pragma unroll
  for (int r = 0; r < 4; ++r) {
    int gr = kc * 2048 + r * 512 + wg * 16 + jj;
    bias4[r] = b_ih[gr] + b_hh[gr];
  }

  // ---- token parity bits for this lane's two examples ----
  const int bA = lane & 15, bB = 16 + bA;
  unsigned parA[16], parB[16];
  #pragma unroll
  for (int w = 0; w < 16; ++w) {
    unsigned pa = 0, pb = 0;
    for (int bb = 0; bb < 32; ++bb) {
      pa |= (unsigned)(x[bA * S_N + w * 32 + bb] & 1) << bb;
      pb |= (unsigned)(x[bB * S_N + w * 32 + bb] & 1) << bb;
    }
    parA[w] = pa; parB[w] = pb;
  }

  float csA = 0.f, csB = 0.f;              // c_state for (jj, bA) / (jj, bB)

  for (int t = 0; t < S_N; ++t) {
    // ---- stage emb_t: 1 x 16B cached load/thread (512 chunks) ----
    {
      const f32x4* e16 = (const f32x4*)(emb + (size_t)t * B_N * D_E);
      int ex = tid >> 4, col = tid & 15;
      *(f32x4*)((char*)&Bl[0][0] + ex * 1296 + col * 16) = e16[tid];
    }
    // ---- stage h_prev: masked 16-B sentinel poll, per-u32 check ----
    if (t == 0) {
      for (int i = tid; i < 4096; i += 512) {
        int b = i >> 7, hh = i & 127;
        *(u64*)&Bl[b][128 + hh * 4] = 0ull;
      }
    } else {
      const char* srcb = (const char*)hs + (size_t)(t - 1) * 32768;
      U128 buf[4];
      unsigned pend = 0xFu;
      while (pend) {
        #pragma unroll
        for (int c = 0; c < 4; ++c)
          if (pend & (1u << c))
            asm volatile("global_load_dwordx4 %0, %1, off sc0 sc1"
                         : "=v"(buf[c].f) : "v"(srcb + (c * 8192 + tid * 16)) : "memory");
        asm volatile("s_waitcnt vmcnt(0)" ::: "memory");
        __builtin_amdgcn_sched_barrier(0);
        #pragma unroll
        for (int c = 0; c < 4; ++c)
          if ((pend & (1u << c)) &&
              buf[c].w[0] != SENT32 && buf[c].w[1] != SENT32 &&
              buf[c].w[2] != SENT32 && buf[c].w[3] != SENT32) {
            int ci = c * 512 + tid;        // chunk 0..2047
            *(f32x4*)((char*)&Bl[0][0] + (ci >> 6) * 1296 + 256 + (ci & 63) * 16) = buf[c].f;
            pend &= ~(1u << c);
          }
      }
    }
    __syncthreads();                 // A: B ready

    // ---- MFMA: wave wv, remapped 16 rows x 32 ex over full K=640 ----
    f32x4 acc0 = {0.f,0.f,0.f,0.f}, acc1 = {0.f,0.f,0.f,0.f};
    #pragma unroll
    for (int ks = 0; ks < 20; ++ks) {
      int cb = (ks * 32 + lk) * 2;         // byte offset in a row
      short8 b0 = *(const short8*)((const char*)&Bl[0][0] + lrow * 1296 + cb);
      short8 b1 = *(const short8*)((const char*)&Bl[0][0] + (16 + lrow) * 1296 + cb);
      acc0 = __builtin_amdgcn_mfma_f32_16x16x32_bf16(Afrag[ks], b0, acc0, 0, 0, 0);
      acc1 = __builtin_amdgcn_mfma_f32_16x16x32_bf16(Afrag[ks], b1, acc1, 0, 0, 0);
    }

    // ---- register epilogue + per-wave EARLY publish ----
    {
      float iA = 1.f / (1.f + __expf(-(acc0[0] + bias4[0])));
      float fA = 1.f / (1.f + __expf(-(acc0[1] + bias4[1])));
      float gA = ftanh(acc0[2] + bias4[2]);
      float oA = 1.f / (1.f + __expf(-(acc0[3] + bias4[3])));
      float cnA = fA * csA + iA * gA;
      float hnA = oA * ftanh(cnA);

      float iB = 1.f / (1.f + __expf(-(acc1[0] + bias4[0])));
      float fB = 1.f / (1.f + __expf(-(acc1[1] + bias4[1])));
      float gB = ftanh(acc1[2] + bias4[2]);
      float oB = 1.f / (1.f + __expf(-(acc1[3] + bias4[3])));
      float cnB = fB * csB + iB * gB;
      float hnB = oB * ftanh(cnB);

      float pcA = __shfl_xor(cnA, 32), phA = __shfl_xor(hnA, 32);
      float pcB = __shfl_xor(cnB, 32), phB = __shfl_xor(hnB, 32);

      float c0A = kc ? pcA : cnA, c1A = kc ? cnA : pcA;
      float h0A = kc ? phA : hnA, h1A = kc ? hnA : phA;
      float c0B = kc ? pcB : cnB, c1B = kc ? cnB : pcB;
      float h0B = kc ? phB : hnB, h1B = kc ? hnB : phB;

      int selA = (parA[t >> 5] >> (t & 31)) & 1;
      int selB = (parB[t >> 5] >> (t & 31)) & 1;
      csA = selA ? c1A : c0A;  float hA = selA ? h1A : h0A;
      csB = selB ? c1B : c0B;  float hB = selB ? h1B : h0B;

      __hip_bfloat16 ha = __float2bfloat16(hA);
      __hip_bfloat16 hb2 = __float2bfloat16(hB);
      unsigned hA16 = *(const unsigned short*)&ha;
      unsigned hB16 = *(const unsigned short*)&hb2;
      unsigned qA = (unsigned)__shfl_xor((int)hA16, 16);  // partner jp's dim
      unsigned qB = (unsigned)__shfl_xor((int)hB16, 16);
      if (lane < 16) {                     // kc=0, jp=0 lanes publish
        unsigned* h32 = (unsigned*)hs + (size_t)t * 8192;
        unsigned vA = hA16 | (qA << 16);   // dims (wv*2, wv*2+1), ex=lane
        unsigned vB = hB16 | (qB << 16);   // ex = lane+16
        __hip_atomic_store(h32 + lane * 256 + wg * 8 + wv, vA,
                           __ATOMIC_RELAXED, __HIP_MEMORY_SCOPE_AGENT);
        __hip_atomic_store(h32 + (lane + 16) * 256 + wg * 8 + wv, vB,
                           __ATOMIC_RELAXED, __HIP_MEMORY_SCOPE_AGENT);
      }
    }
    __syncthreads();                 // C: all Bl reads done before next staging
  }
}

// ------------------------------------------------------------------
// logits GEMM: M=16384, N=10000(pad 10112), K=512, bf16 MFMA, +bias.
// Staging: global_load_lds width-16 into LINEAR [128][64] tiles with
// source-side XOR swizzle (chunk position = logical ^ (row&7)); fragment
// reads apply the same XOR -> conflict-free (2-way). Logits written bf16
// into each row's own out-slot second half; deterministic rowpart.
__launch_bounds__(256, 2)
__global__ void k_gemm(const __hip_bfloat16* __restrict__ hs,
                       const __hip_bfloat16* __restrict__ wout,   // padded V_PAD rows
                       const float* __restrict__ b_out,
                       float* __restrict__ out,
                       float* __restrict__ rowpart)   // [16384][80]
{
  __shared__ __align__(16) char AlB[16384];   // [128][64] bf16, swizzled chunks
  __shared__ __align__(16) char WtB[16384];
  __shared__ float sumLDS[2][128];            // [nq][row_local]
  const int tid = threadIdx.x;
  const int tn = blockIdx.x, tm = blockIdx.y;
  const int lane = tid & 63, wv = tid >> 6;
  const int mq = wv & 1, nq = wv >> 1;
  const int lrow = lane & 15;
  const int swz = lrow & 7;
  f32x4 acc[4][4] = {};

  const int ci0 = wv * 64 + lane;          // within-group chunk id
  for (int k0 = 0; k0 < 512; k0 += 64) {
    __syncthreads();                       // prior MFMA reads complete
    #pragma unroll
    for (int g2 = 0; g2 < 4; ++g2) {
      int ci = g2 * 256 + ci0;             // 0..1023
      int row = ci >> 3, pos = ci & 7;
      int lc  = pos ^ (row & 7);           // pre-swizzled source chunk
      const __hip_bfloat16* ga = hs + ((size_t)(tm * 128 + row)) * 512 + k0 + lc * 8;
      __builtin_amdgcn_global_load_lds((gas_u32*)ga,
          (las_u32*)(AlB + ci * 16), 16, 0, 0);
      const __hip_bfloat16* gw = wout + ((size_t)(tn * 128 + row)) * 512 + k0 + lc * 8;
      __builtin_amdgcn_global_load_lds((gas_u32*)gw,
          (las_u32*)(WtB + ci * 16), 16, 0, 0);
    }
    asm volatile("s_waitcnt vmcnt(0)" ::: "memory");
    __syncthreads();

    #pragma unroll
    for (int ks = 0; ks < 2; ++ks) {
      int q = ks * 4 + (lane >> 4);        // logical chunk in row
      int p16 = (q ^ swz) << 4;            // swizzled byte offset
      short8 af[4], bf[4];
      #pragma unroll
      for (int i = 0; i < 4; ++i)
        af[i] = *(const short8*)(AlB + (mq * 64 + i * 16 + lrow) * 128 + p16);
      #pragma unroll
      for (int i = 0; i < 4; ++i)
        bf[i] = *(const short8*)(WtB + (nq * 64 + i * 16 + lrow) * 128 + p16);
      #pragma unroll
      for (int i = 0; i < 4; ++i)
        #pragma unroll
        for (int jx = 0; jx < 4; ++jx)
          acc[i][jx] = __builtin_amdgcn_mfma_f32_16x16x32_bf16(af[i], bf[jx], acc[i][jx], 0, 0, 0);
    }
  }
  const int rbase = tm * 128 + mq * 64 + (lane >> 4) * 4;
  const int cbase = tn * 128 + nq * 64 + (lane & 15);
  float esum[4][4];
  #pragma unroll
  for (int i = 0; i < 4; ++i)
    #pragma unroll
    for (int r = 0; r < 4; ++r) esum[i][r] = 0.f;

  #pragma unroll
  for (int i = 0; i < 4; ++i) {
    #pragma unroll
    for (int jx = 0; jx < 4; ++jx) {
      int col = cbase + jx * 16;
      if (col < V_N) {
        float bo = b_out[col];
        #pragma unroll
        for (int r = 0; r < 4; ++r) {
          int row = rbase + i * 16 + r;
          float lg = acc[i][jx][r] + bo;
          __hip_bfloat16* lrow16 =
            (__hip_bfloat16*)((char*)out + (size_t)row * (V_N * 4) + V_N * 2);
          lrow16[col] = __float2bfloat16(lg);
          esum[i][r] += __expf(lg);
        }
      }
    }
  }
  #pragma unroll
  for (int i = 0; i < 4; ++i) {
    #pragma unroll
    for (int r = 0; r < 4; ++r) {
      float s = esum[i][r];
      s += __shfl_xor(s, 1); s += __shfl_xor(s, 2);
      s += __shfl_xor(s, 4); s += __shfl_xor(s, 8);
      if ((lane & 15) == 0)
        sumLDS[nq][mq * 64 + i * 16 + (lane >> 4) * 4 + r] = s;
    }
  }
  __syncthreads();
  if (tid < 128)   // one plain store per (row, tile): deterministic slot
    rowpart[(size_t)(tm * 128 + tid) * 80 + tn] = sumLDS[0][tid] + sumLDS[1][tid];
}

// ------------------------------------------------------------------
// fix-up: lse[r] = log(sum of 79 partials, fixed order); read own row's
// bf16 logits into registers, sync (self-overlap safety), write f32.
__launch_bounds__(256)
__global__ void k_lsm_fix(float* __restrict__ out, const float* __restrict__ rowpart) {
  const int r = blockIdx.x;
  const int tid = threadIdx.x;
  const float* rp = rowpart + (size_t)r * 80;
  float s = 0.f;
  for (int p = 0; p < 79; ++p) s += rp[p];   // same order in every thread/replay
  float lse = __logf(s);

  const f32x4* src = (const f32x4*)((const char*)out + (size_t)r * (V_N * 4) + V_N * 2);
  U128 c[5];
  #pragma unroll
  for (int i = 0; i < 5; ++i) {
    int idx = tid + i * 256;
    if (idx < 1250) c[i].f = src[idx];       // 1250 x 16B = 10000 bf16
  }
  __syncthreads();                           // all reads done before any write
  float* dst = out + (size_t)r * V_N;
  #pragma unroll
  for (int i = 0; i < 5; ++i) {
    int idx = tid + i * 256;
    if (idx < 1250) {
      const unsigned short* u = (const unsigned short*)&c[i];
      float4 lo, hi;
      lo.x = __uint_as_float((unsigned)u[0] << 16) - lse;
      lo.y = __uint_as_float((unsigned)u[1] << 16) - lse;
      lo.z = __uint_as_float((unsigned)u[2] << 16) - lse;
      lo.w = __uint_as_float((unsigned)u[3] << 16) - lse;
      hi.x = __uint_as_float((unsigned)u[4] << 16) - lse;
      hi.y = __uint_as_float((unsigned)u[5] << 16) - lse;
      hi.z = __uint_as_float((unsigned)u[6] << 16) - lse;
      hi.w = __uint_as_float((unsigned)u[7] << 16) - lse;
      *(float4*)(dst + idx * 8)     = lo;
      *(float4*)(dst + idx * 8 + 4) = hi;
    }
  }
}

// ------------------------------------------------------------------
extern "C" void kernel_launch(void* const* d_in, const int* in_sizes, int n_in,
                              void* d_out, int out_size, void* d_ws, size_t ws_size,
                              hipStream_t stream) {
  const int*   x    = (const int*)d_in[0];
  const float* tab  = (const float*)d_in[1];
  const float* Wih  = (const float*)d_in[2];
  const float* Whh  = (const float*)d_in[3];
  const float* bih  = (const float*)d_in[4];
  const float* bhh  = (const float*)d_in[5];
  const float* Wout = (const float*)d_in[6];
  const float* bout = (const float*)d_in[7];
  float* out = (float*)d_out;

  char* ws = (char*)d_ws;
  float*           rowpart = (float*)(ws + OFF_RP);
  __hip_bfloat16*  emb     = (__hip_bfloat16*)(ws + OFF_EMB);
  __hip_bfloat16*  hsbuf   = (__hip_bfloat16*)(ws + OFF_HS);
  __hip_bfloat16*  wob     = (__hip_bfloat16*)(ws + OFF_WOUT);

  // re-poison hs to the write-once sentinel every launch (replay-safe)
  hipMemsetAsync(hsbuf, 0xFF, (size_t)S_N * B_N * H_N * 2, stream);
  k_prep_emb<<<(S_N * B_N * D_E) / 256, 256, 0, stream>>>(x, tab, emb);
  k_prep_wout<<<(V_PAD * H_N) / 256, 256, 0, stream>>>(Wout, wob);
  k_recurrence<<<32, 512, 0, stream>>>(x, Wih, Whh, bih, bhh, emb, hsbuf);
  k_gemm<<<dim3(79, 128), 256, 0, stream>>>(hsbuf, wob, bout, out, rowpart);
  k_lsm_fix<<<16384, 256, 0, stream>>>(out, rowpart);
}

// Round 17
// 2224.928 us; speedup vs baseline: 1.2165x; 1.0245x over previous
//
#include <hip/hip_runtime.h>
#include <hip/hip_bf16.h>

typedef __attribute__((ext_vector_type(8))) short short8;
typedef __attribute__((ext_vector_type(4))) float f32x4;
typedef unsigned long long u64;

#define V_N 10000
#define V_PAD 10112                      // 79*128, padded for gload_lds staging
#define D_E 128
#define H_N 512
#define B_N 32
#define S_N 512

#define SENT64 0xFFFFFFFFFFFFFFFFull   // bf16 NaN pattern: unreachable for finite h

// ---- workspace layout (bytes) ----
#define OFF_RP    0                        // rowpart: 16384 x 80 f32 = 5,242,880
#define OFF_EMB   5242880                  // S*B*D bf16 = 4,194,304
#define OFF_HS    (OFF_EMB + 4194304)      // S*B*H bf16 = 16,777,216
#define OFF_WOUT  (OFF_HS + 16777216)      // V_PAD*H bf16 = 10,354,688

typedef __attribute__((address_space(1))) const unsigned gas_u32;
typedef __attribute__((address_space(3))) unsigned las_u32;

// ------------------------------------------------------------------
__device__ __forceinline__ float ftanh(float x) {
  float e = __expf(-2.f * fabsf(x));          // in (0,1], overflow-safe
  float r = (1.f - e) / (1.f + e);
  return __builtin_copysignf(r, x);
}

union U128 { f32x4 f; u64 q[2]; unsigned w[4]; };

// ------------------------------------------------------------------
// prep: embedding gather -> bf16 [s][b][d]
__global__ void k_prep_emb(const int* __restrict__ x, const float* __restrict__ tab,
                           __hip_bfloat16* __restrict__ emb) {
  int i = blockIdx.x * 256 + threadIdx.x;         // over S*B*D = 2,097,152
  if (i >= S_N * B_N * D_E) return;
  int d  = i & (D_E - 1);
  int sb = i >> 7;
  int b  = sb & (B_N - 1);
  int s  = sb >> 5;
  int tok = x[b * S_N + s];
  emb[i] = __float2bfloat16(tab[tok * D_E + d]);
}

// prep: W_out -> bf16, zero-padded to V_PAD rows
__global__ void k_prep_wout(const float* __restrict__ w, __hip_bfloat16* __restrict__ o) {
  int i = blockIdx.x * 256 + threadIdx.x;         // over V_PAD*H
  if (i >= V_PAD * H_N) return;
  o[i] = (i < V_N * H_N) ? __float2bfloat16(w[i]) : __float2bfloat16(0.f);
}

// ------------------------------------------------------------------
// persistent recurrence: 32 WGs x 512 threads, register epilogue (r15,
// verbatim). Wave wv owns h-dims jj=wv*2, wv*2+1 via remapped A-rows
// (row -> kc=row>>3, jp=(row>>2)&1, gate=row&3). LSTM pointwise math in
// registers; cells exchange candidates with one shfl_xor(32); h lands in
// hloc; publish = 128 coalesced u64 bypass stores (fire-and-forget).
// Consumers poll the data itself (16-B chunks vs u64 sentinels).
__launch_bounds__(512, 1)
__global__ void k_recurrence(const int* __restrict__ x,
                             const float* __restrict__ W_ih, const float* __restrict__ W_hh,
                             const float* __restrict__ b_ih, const float* __restrict__ b_hh,
                             const __hip_bfloat16* __restrict__ emb,
                             __hip_bfloat16* __restrict__ hs)     // [512][32][512]
{
  __shared__ __align__(16) __hip_bfloat16 Bl[32][648];  // [example][emb128 ; h512]
  __shared__ unsigned short hloc[16][32];  // [jj][ex] bf16 bits of new h

  const int tid = threadIdx.x;
  const int wg  = blockIdx.x;              // 0..31
  const int lane = tid & 63, wv = tid >> 6;       // wv = wave 0..7
  const int lrow = lane & 15, lk = (lane >> 4) * 8;

  // ---- one-time: A-fragments (16 remapped rows x full K 640) ----
  short8 Afrag[20];                        // 80 VGPRs
  {
    int kcA = lrow >> 3, jpA = (lrow >> 2) & 1, gateA = lrow & 3;
    int grow = kcA * 2048 + gateA * 512 + wg * 16 + wv * 2 + jpA;
    #pragma unroll
    for (int ks = 0; ks < 20; ++ks) {
      int c0 = ks * 32 + lk;
      short8 a;
      #pragma unroll
      for (int e = 0; e < 8; ++e) {
        int c = c0 + e;
        float v = (c < 128) ? W_ih[(size_t)grow * 128 + c]
                            : W_hh[(size_t)grow * 512 + (c - 128)];
        __hip_bfloat16 hb = __float2bfloat16(v);
        a[e] = *(const short*)&hb;
      }
      Afrag[ks] = a;
    }
  }

  // ---- output mapping: lane (g=l>>4, c=l&15) ----
  const int g  = lane >> 4;
  const int kc = g >> 1, jp = g & 1;
  const int jj = wv * 2 + jp;
  float bias4[4];
  #pragma unroll
  for (int r = 0; r < 4; ++r) {
    int gr = kc * 2048 + r * 512 + wg * 16 + jj;
    bias4[r] = b_ih[gr] + b_hh[gr];
  }

  // ---- token parity bits for this lane's two examples ----
  const int bA = lane & 15, bB = 16 + bA;
  unsigned parA[16], parB[16];
  #pragma unroll
  for (int w = 0; w < 16; ++w) {
    unsigned pa = 0, pb = 0;
    for (int bb = 0; bb < 32; ++bb) {
      pa |= (unsigned)(x[bA * S_N + w * 32 + bb] & 1) << bb;
      pb |= (unsigned)(x[bB * S_N + w * 32 + bb] & 1) << bb;
    }
    parA[w] = pa; parB[w] = pb;
  }

  float csA = 0.f, csB = 0.f;              // c_state for (jj, bA) / (jj, bB)

  for (int t = 0; t < S_N; ++t) {
    // ---- stage emb_t: 1 x 16B cached load/thread (512 chunks) ----
    {
      const f32x4* e16 = (const f32x4*)(emb + (size_t)t * B_N * D_E);
      int ex = tid >> 4, col = tid & 15;
      *(f32x4*)((char*)&Bl[0][0] + ex * 1296 + col * 16) = e16[tid];
    }
    // ---- stage h_prev: masked 16-B sentinel poll, 4 chunks/thread ----
    if (t == 0) {
      for (int i = tid; i < 4096; i += 512) {
        int b = i >> 7, hh = i & 127;
        *(u64*)&Bl[b][128 + hh * 4] = 0ull;
      }
    } else {
      const char* srcb = (const char*)hs + (size_t)(t - 1) * 32768;
      U128 buf[4];
      unsigned pend = 0xFu;
      while (pend) {
        #pragma unroll
        for (int c = 0; c < 4; ++c)
          if (pend & (1u << c))
            asm volatile("global_load_dwordx4 %0, %1, off sc0 sc1"
                         : "=v"(buf[c].f) : "v"(srcb + (c * 8192 + tid * 16)) : "memory");
        asm volatile("s_waitcnt vmcnt(0)" ::: "memory");
        __builtin_amdgcn_sched_barrier(0);
        #pragma unroll
        for (int c = 0; c < 4; ++c)
          if ((pend & (1u << c)) && buf[c].q[0] != SENT64 && buf[c].q[1] != SENT64) {
            int ci = c * 512 + tid;        // chunk 0..2047
            *(f32x4*)((char*)&Bl[0][0] + (ci >> 6) * 1296 + 256 + (ci & 63) * 16) = buf[c].f;
            pend &= ~(1u << c);
          }
      }
    }
    __syncthreads();                 // A: B ready

    // ---- MFMA: wave wv, remapped 16 rows x 32 ex over full K=640 ----
    f32x4 acc0 = {0.f,0.f,0.f,0.f}, acc1 = {0.f,0.f,0.f,0.f};
    #pragma unroll
    for (int ks = 0; ks < 20; ++ks) {
      int cb = (ks * 32 + lk) * 2;         // byte offset in a row
      short8 b0 = *(const short8*)((const char*)&Bl[0][0] + lrow * 1296 + cb);
      short8 b1 = *(const short8*)((const char*)&Bl[0][0] + (16 + lrow) * 1296 + cb);
      acc0 = __builtin_amdgcn_mfma_f32_16x16x32_bf16(Afrag[ks], b0, acc0, 0, 0, 0);
      acc1 = __builtin_amdgcn_mfma_f32_16x16x32_bf16(Afrag[ks], b1, acc1, 0, 0, 0);
    }

    // ---- register epilogue: own-cell candidates + shfl_xor(32) swap ----
    {
      float iA = 1.f / (1.f + __expf(-(acc0[0] + bias4[0])));
      float fA = 1.f / (1.f + __expf(-(acc0[1] + bias4[1])));
      float gA = ftanh(acc0[2] + bias4[2]);
      float oA = 1.f / (1.f + __expf(-(acc0[3] + bias4[3])));
      float cnA = fA * csA + iA * gA;
      float hnA = oA * ftanh(cnA);

      float iB = 1.f / (1.f + __expf(-(acc1[0] + bias4[0])));
      float fB = 1.f / (1.f + __expf(-(acc1[1] + bias4[1])));
      float gB = ftanh(acc1[2] + bias4[2]);
      float oB = 1.f / (1.f + __expf(-(acc1[3] + bias4[3])));
      float cnB = fB * csB + iB * gB;
      float hnB = oB * ftanh(cnB);

      float pcA = __shfl_xor(cnA, 32), phA = __shfl_xor(hnA, 32);
      float pcB = __shfl_xor(cnB, 32), phB = __shfl_xor(hnB, 32);

      float c0A = kc ? pcA : cnA, c1A = kc ? cnA : pcA;
      float h0A = kc ? phA : hnA, h1A = kc ? hnA : phA;
      float c0B = kc ? pcB : cnB, c1B = kc ? cnB : pcB;
      float h0B = kc ? phB : hnB, h1B = kc ? hnB : phB;

      int selA = (parA[t >> 5] >> (t & 31)) & 1;
      int selB = (parB[t >> 5] >> (t & 31)) & 1;
      csA = selA ? c1A : c0A;  float hA = selA ? h1A : h0A;
      csB = selB ? c1B : c0B;  float hB = selB ? h1B : h0B;

      if (kc == 0) {
        __hip_bfloat16 ha = __float2bfloat16(hA);
        __hip_bfloat16 hb2 = __float2bfloat16(hB);
        hloc[jj][bA] = *(const unsigned short*)&ha;
        hloc[jj][bB] = *(const unsigned short*)&hb2;
      }
    }
    __syncthreads();                 // C: hloc ready; all Bl reads done

    // ---- publish h(t) into hs[t]: fire-and-forget coalesced u64 stores ----
    if (tid < 128) {                 // 32 ex x 4 u64 (=16 dims) per WG
      int ex = tid >> 2, part = tid & 3;
      u64 v = (u64)hloc[part * 4 + 0][ex]
            | ((u64)hloc[part * 4 + 1][ex] << 16)
            | ((u64)hloc[part * 4 + 2][ex] << 32)
            | ((u64)hloc[part * 4 + 3][ex] << 48);
      u64* dst = (u64*)hs + (size_t)t * 4096 + ex * 128 + wg * 4 + part;
      __hip_atomic_store(dst, v, __ATOMIC_RELAXED, __HIP_MEMORY_SCOPE_AGENT);
    }
    // no wait, no flag: consumers poll the data itself
  }
}

// ------------------------------------------------------------------
// logits GEMM: M=16384, N=10000(pad 10112), K=512, bf16 MFMA, +bias.
// Staging: global_load_lds width-16 into LINEAR [128][64] tiles with
// source-side XOR swizzle (chunk position = logical ^ (row&7)); fragment
// reads apply the same XOR -> conflict-free. Logits written bf16 into
// each row's own out-slot second half; deterministic rowpart.
__launch_bounds__(256, 2)
__global__ void k_gemm(const __hip_bfloat16* __restrict__ hs,
                       const __hip_bfloat16* __restrict__ wout,   // padded V_PAD rows
                       const float* __restrict__ b_out,
                       float* __restrict__ out,
                       float* __restrict__ rowpart)   // [16384][80]
{
  __shared__ __align__(16) char AlB[16384];   // [128][64] bf16, swizzled chunks
  __shared__ __align__(16) char WtB[16384];
  __shared__ float sumLDS[2][128];            // [nq][row_local]
  const int tid = threadIdx.x;
  const int tn = blockIdx.x, tm = blockIdx.y;
  const int lane = tid & 63, wv = tid >> 6;
  const int mq = wv & 1, nq = wv >> 1;
  const int lrow = lane & 15;
  const int swz = lrow & 7;
  f32x4 acc[4][4] = {};

  const int ci0 = wv * 64 + lane;          // within-group chunk id
  for (int k0 = 0; k0 < 512; k0 += 64) {
    __syncthreads();                       // prior MFMA reads complete
    #pragma unroll
    for (int g2 = 0; g2 < 4; ++g2) {
      int ci = g2 * 256 + ci0;             // 0..1023
      int row = ci >> 3, pos = ci & 7;
      int lc  = pos ^ (row & 7);           // pre-swizzled source chunk
      const __hip_bfloat16* ga = hs + ((size_t)(tm * 128 + row)) * 512 + k0 + lc * 8;
      __builtin_amdgcn_global_load_lds((gas_u32*)ga,
          (las_u32*)(AlB + ci * 16), 16, 0, 0);
      const __hip_bfloat16* gw = wout + ((size_t)(tn * 128 + row)) * 512 + k0 + lc * 8;
      __builtin_amdgcn_global_load_lds((gas_u32*)gw,
          (las_u32*)(WtB + ci * 16), 16, 0, 0);
    }
    asm volatile("s_waitcnt vmcnt(0)" ::: "memory");
    __syncthreads();

    #pragma unroll
    for (int ks = 0; ks < 2; ++ks) {
      int q = ks * 4 + (lane >> 4);        // logical chunk in row
      int p16 = (q ^ swz) << 4;            // swizzled byte offset
      short8 af[4], bf[4];
      #pragma unroll
      for (int i = 0; i < 4; ++i)
        af[i] = *(const short8*)(AlB + (mq * 64 + i * 16 + lrow) * 128 + p16);
      #pragma unroll
      for (int i = 0; i < 4; ++i)
        bf[i] = *(const short8*)(WtB + (nq * 64 + i * 16 + lrow) * 128 + p16);
      #pragma unroll
      for (int i = 0; i < 4; ++i)
        #pragma unroll
        for (int jx = 0; jx < 4; ++jx)
          acc[i][jx] = __builtin_amdgcn_mfma_f32_16x16x32_bf16(af[i], bf[jx], acc[i][jx], 0, 0, 0);
    }
  }
  const int rbase = tm * 128 + mq * 64 + (lane >> 4) * 4;
  const int cbase = tn * 128 + nq * 64 + (lane & 15);
  float esum[4][4];
  #pragma unroll
  for (int i = 0; i < 4; ++i)
    #pragma unroll
    for (int r = 0; r < 4; ++r) esum[i][r] = 0.f;

  #pragma unroll
  for (int i = 0; i < 4; ++i) {
    #pragma unroll
    for (int jx = 0; jx < 4; ++jx) {
      int col = cbase + jx * 16;
      if (col < V_N) {
        float bo = b_out[col];
        #pragma unroll
        for (int r = 0; r < 4; ++r) {
          int row = rbase + i * 16 + r;
          float lg = acc[i][jx][r] + bo;
          __hip_bfloat16* lrow16 =
            (__hip_bfloat16*)((char*)out + (size_t)row * (V_N * 4) + V_N * 2);
          lrow16[col] = __float2bfloat16(lg);
          esum[i][r] += __expf(lg);
        }
      }
    }
  }
  #pragma unroll
  for (int i = 0; i < 4; ++i) {
    #pragma unroll
    for (int r = 0; r < 4; ++r) {
      float s = esum[i][r];
      s += __shfl_xor(s, 1); s += __shfl_xor(s, 2);
      s += __shfl_xor(s, 4); s += __shfl_xor(s, 8);
      if ((lane & 15) == 0)
        sumLDS[nq][mq * 64 + i * 16 + (lane >> 4) * 4 + r] = s;
    }
  }
  __syncthreads();
  if (tid < 128)   // one plain store per (row, tile): deterministic slot
    rowpart[(size_t)(tm * 128 + tid) * 80 + tn] = sumLDS[0][tid] + sumLDS[1][tid];
}

// ------------------------------------------------------------------
// fix-up: lse[r] = log(sum of 79 partials, fixed order); read own row's
// bf16 logits into registers, sync (self-overlap safety), write f32.
__launch_bounds__(256)
__global__ void k_lsm_fix(float* __restrict__ out, const float* __restrict__ rowpart) {
  const int r = blockIdx.x;
  const int tid = threadIdx.x;
  const float* rp = rowpart + (size_t)r * 80;
  float s = 0.f;
  for (int p = 0; p < 79; ++p) s += rp[p];   // same order in every thread/replay
  float lse = __logf(s);

  const f32x4* src = (const f32x4*)((const char*)out + (size_t)r * (V_N * 4) + V_N * 2);
  U128 c[5];
  #pragma unroll
  for (int i = 0; i < 5; ++i) {
    int idx = tid + i * 256;
    if (idx < 1250) c[i].f = src[idx];       // 1250 x 16B = 10000 bf16
  }
  __syncthreads();                           // all reads done before any write
  float* dst = out + (size_t)r * V_N;
  #pragma unroll
  for (int i = 0; i < 5; ++i) {
    int idx = tid + i * 256;
    if (idx < 1250) {
      const unsigned short* u = (const unsigned short*)&c[i];
      float4 lo, hi;
      lo.x = __uint_as_float((unsigned)u[0] << 16) - lse;
      lo.y = __uint_as_float((unsigned)u[1] << 16) - lse;
      lo.z = __uint_as_float((unsigned)u[2] << 16) - lse;
      lo.w = __uint_as_float((unsigned)u[3] << 16) - lse;
      hi.x = __uint_as_float((unsigned)u[4] << 16) - lse;
      hi.y = __uint_as_float((unsigned)u[5] << 16) - lse;
      hi.z = __uint_as_float((unsigned)u[6] << 16) - lse;
      hi.w = __uint_as_float((unsigned)u[7] << 16) - lse;
      *(float4*)(dst + idx * 8)     = lo;
      *(float4*)(dst + idx * 8 + 4) = hi;
    }
  }
}

// ------------------------------------------------------------------
extern "C" void kernel_launch(void* const* d_in, const int* in_sizes, int n_in,
                              void* d_out, int out_size, void* d_ws, size_t ws_size,
                              hipStream_t stream) {
  const int*   x    = (const int*)d_in[0];
  const float* tab  = (const float*)d_in[1];
  const float* Wih  = (const float*)d_in[2];
  const float* Whh  = (const float*)d_in[3];
  const float* bih  = (const float*)d_in[4];
  const float* bhh  = (const float*)d_in[5];
  const float* Wout = (const float*)d_in[6];
  const float* bout = (const float*)d_in[7];
  float* out = (float*)d_out;

  char* ws = (char*)d_ws;
  float*           rowpart = (float*)(ws + OFF_RP);
  __hip_bfloat16*  emb     = (__hip_bfloat16*)(ws + OFF_EMB);
  __hip_bfloat16*  hsbuf   = (__hip_bfloat16*)(ws + OFF_HS);
  __hip_bfloat16*  wob     = (__hip_bfloat16*)(ws + OFF_WOUT);

  // re-poison hs to the write-once sentinel every launch (replay-safe)
  hipMemsetAsync(hsbuf, 0xFF, (size_t)S_N * B_N * H_N * 2, stream);
  k_prep_emb<<<(S_N * B_N * D_E) / 256, 256, 0, stream>>>(x, tab, emb);
  k_prep_wout<<<(V_PAD * H_N) / 256, 256, 0, stream>>>(Wout, wob);
  k_recurrence<<<32, 512, 0, stream>>>(x, Wih, Whh, bih, bhh, emb, hsbuf);
  k_gemm<<<dim3(79, 128), 256, 0, stream>>>(hsbuf, wob, bout, out, rowpart);
  k_lsm_fix<<<16384, 256, 0, stream>>>(out, rowpart);
}